// Round 11
// baseline (195.709 us; speedup 1.0000x reference)
//
#include <hip/hip_runtime.h>
#include <math.h>

#define NROWS 32768
#define NE    1024
#define CDIM  256
#define ZB_STRIDE 262144

#define ZQ_OFF   0
#define LOSS_OFF 8388608
#define PERP_OFF 8388609
#define ENC_OFF  8388610
#define IDX_OFF  41943042

#define THETA 1.0e-4f
// e scaled by 2^12 before fp16 conversion; -2*dot = -2^-11 * acc
#define NEG2_SCALE (-0.00048828125f)

typedef _Float16 f16x8 __attribute__((ext_vector_type(8)));
typedef __attribute__((ext_vector_type(4))) float f32x4;
typedef __attribute__((ext_vector_type(8))) unsigned short ushort8;

// RNE float -> fp16 bits
__device__ __forceinline__ unsigned short f2h(float x) {
  _Float16 h = (_Float16)x;
  unsigned short u;
  __builtin_memcpy(&u, &h, 2);
  return u;
}

// ---------------------------------------------------------------------------
// numpy-pairwise-exact sum of squares (stride 1)
__device__ __forceinline__ float np_sumsq_256_s1(const float* __restrict__ base) {
  float tot[2];
#pragma unroll
  for (int hh = 0; hh < 2; ++hh) {
    float r[8];
#pragma unroll
    for (int j = 0; j < 8; ++j) {
      float x = base[hh * 128 + j];
      r[j] = __fmul_rn(x, x);
    }
    for (int i = 8; i < 128; i += 8) {
#pragma unroll
      for (int j = 0; j < 8; ++j) {
        float x = base[hh * 128 + i + j];
        r[j] = __fadd_rn(r[j], __fmul_rn(x, x));
      }
    }
    tot[hh] = __fadd_rn(__fadd_rn(__fadd_rn(r[0], r[1]), __fadd_rn(r[2], r[3])),
                        __fadd_rn(__fadd_rn(r[4], r[5]), __fadd_rn(r[6], r[7])));
  }
  return __fadd_rn(tot[0], tot[1]);
}

// ---------------------------------------------------------------------------
// Fused emb prep (role-split):
// blocks [0,128): fp32 -> fp16*2^12 in MFMA-fragment order
// blocks [128,384): emb -> embT fp32 transpose (for repair)
// blocks [384,388): numpy-exact enorm
__global__ __launch_bounds__(256) void prep_e(const float* __restrict__ emb,
                                              unsigned short* __restrict__ ef16r,
                                              float* __restrict__ embT,
                                              float* __restrict__ enorm) {
  const int bid = blockIdx.x;
  if (bid < 128) {
    int cid = bid * 256 + threadIdx.x;   // 0..32767
    int e = cid >> 5, cc = cid & 31;
    int kc = cc >> 2, g = cc & 3;
    int c0 = kc * 32 + g * 8;
    ushort8 o;
#pragma unroll
    for (int el = 0; el < 8; ++el) o[el] = f2h(emb[(size_t)e * 256 + c0 + el] * 4096.0f);
    int et = e >> 7, wcb = (e >> 6) & 1, nj = (e >> 4) & 3, l15e = e & 15;
    size_t chunk = ((((size_t)et * 2 + wcb) * 8 + kc) * 4 + nj) * 64 + (size_t)g * 16 + l15e;
    *reinterpret_cast<ushort8*>(ef16r + (chunk << 3)) = o;
  } else if (bid < 384) {
    __shared__ float tile[32][33];
    int tb = bid - 128;
    int be = tb & 31, bc = tb >> 5;
    int tx = threadIdx.x & 31, ty = threadIdx.x >> 5;
#pragma unroll
    for (int i = 0; i < 4; ++i)
      tile[ty + 8 * i][tx] = emb[(size_t)(be * 32 + ty + 8 * i) * 256 + bc * 32 + tx];
    __syncthreads();
#pragma unroll
    for (int i = 0; i < 4; ++i)
      embT[(size_t)(bc * 32 + ty + 8 * i) * 1024 + be * 32 + tx] = tile[tx][ty + 8 * i];
  } else {
    int n = (bid - 384) * 256 + threadIdx.x;
    enorm[n] = np_sumsq_256_s1(emb + (size_t)n * CDIM);
  }
}

// ---------------------------------------------------------------------------
// z (b,c,h,w) fp32 -> zf16r (fragment order) + numpy-exact znorm (r4-verified
// accumulator tree).
__global__ __launch_bounds__(256) void convert_z_kernel(const float* __restrict__ z,
                                                        unsigned short* __restrict__ zf16r,
                                                        float* __restrict__ znorm) {
  __shared__ unsigned short T16[64][266];
  __shared__ float accsF[2][8][16][4];
  const int t = threadIdx.x;
  const int b = blockIdx.x >> 4, hwt = blockIdx.x & 15;
  const int hw0 = hwt * 64;
  const int hw4 = t & 15;
  const int jj = (t >> 4) & 7;
  const int hh = t >> 7;
  const float* zb = z + (size_t)b * ZB_STRIDE + hw0 + hw4 * 4;

  float rr[4];
#pragma unroll
  for (int i = 0; i < 16; ++i) {
    int c = hh * 128 + jj + 8 * i;
    float4 v = *reinterpret_cast<const float4*>(zb + (size_t)c * 1024);
    const float xv[4] = {v.x, v.y, v.z, v.w};
#pragma unroll
    for (int q = 0; q < 4; ++q) {
      float p = __fmul_rn(xv[q], xv[q]);
      rr[q] = (i == 0) ? p : __fadd_rn(rr[q], p);
      T16[hw4 * 4 + q][c] = f2h(xv[q]);
    }
  }
#pragma unroll
  for (int q = 0; q < 4; ++q) accsF[hh][jj][hw4][q] = rr[q];
  __syncthreads();

  if (t < 64) {
    const int h4 = t >> 2, cq = t & 3;
    float tot[2];
#pragma unroll
    for (int half = 0; half < 2; ++half) {
      float r[8];
#pragma unroll
      for (int j = 0; j < 8; ++j) r[j] = accsF[half][j][h4][cq];
      tot[half] = __fadd_rn(__fadd_rn(__fadd_rn(r[0], r[1]), __fadd_rn(r[2], r[3])),
                            __fadd_rn(__fadd_rn(r[4], r[5]), __fadd_rn(r[6], r[7])));
    }
    znorm[b * 1024 + hw0 + t] = __fadd_rn(tot[0], tot[1]);
  }

  // write phase: fragment order
  const int pw = b * 16 + hwt;
  const int panel = pw >> 1, wrh = pw & 1;
  const int l15w = t & 15, gw = (t >> 4) & 3, miw = t >> 6;
  const int rowW = miw * 16 + l15w;
#pragma unroll
  for (int kc = 0; kc < 8; ++kc) {
    ushort8 o;
#pragma unroll
    for (int el = 0; el < 8; ++el) o[el] = T16[rowW][kc * 32 + gw * 8 + el];
    size_t chunk = ((((size_t)panel * 2 + wrh) * 8 + kc) * 4 + miw) * 64 + (size_t)gw * 16 + l15w;
    *reinterpret_cast<ushort8*>(zf16r + (chunk << 3)) = o;
  }
}

// ---------------------------------------------------------------------------
// Register-fragment streaming fp16 MFMA argmin, v8:
//  * r9 mapping (block 128x256e? no: 128 rows x 128 e, grid 2048, 8-way merge)
//  * SINGLE-buffered operands, lean K-loop: acc 64 + af/bv 32 + ptrs ~ 110
//    VGPR; __launch_bounds__(256,4) -> 4 waves/SIMD (r10 diagnosis: 2
//    waves/SIMD at ~270 VGPR could not hide L2 latency -> 8x off floor).
//    Latency hiding via TLP instead of register double-buffering.
//  * setprio removed (independent waves; m190: GEMM null/negative).
//  * znorm/enorm loads deferred to epilogue (not live in K-loop).
//  * MFMA accumulation order bit-identical to r9 -> theta/repair unchanged.
__global__ __launch_bounds__(256, 4) void argmin_tile(
    const unsigned short* __restrict__ zf16r, const unsigned short* __restrict__ ef16r,
    const float* __restrict__ znorm, const float* __restrict__ enorm,
    float* __restrict__ pbd, int* __restrict__ pbi, float* __restrict__ pb2) {
  __shared__ float redd[256];
  __shared__ int   redi[256];
  __shared__ float red2[256];

  const int tid = threadIdx.x;
  const int lane = tid & 63, w = tid >> 6;
  const int wr = w >> 1, wc = w & 1;
  const int l15 = lane & 15, g = lane >> 4;

  // XCD-bijective swizzle: xcd = bid&7; 32 row-panels x 8 e-tiles per XCD
  const int bid = blockIdx.x;
  const int nb = (bid >> 3) & 7;
  const int mb = (bid & 7) * 32 + (bid >> 6);
  const int n0 = mb * 128;
  const int e0 = nb * 128;

  // fragment pointers (u16 units); advance 2048 u16 (4KB) per kc
  const unsigned short* aP = zf16r + (size_t)(mb * 2 + wr) * 16384 + lane * 8;
  const unsigned short* bP = ef16r + (size_t)(nb * 2 + wc) * 16384 + lane * 8;

  f32x4 acc[4][4];
  const f32x4 z4 = {0.f, 0.f, 0.f, 0.f};
#pragma unroll
  for (int mi = 0; mi < 4; ++mi)
#pragma unroll
    for (int nj = 0; nj < 4; ++nj) acc[mi][nj] = z4;

#pragma unroll 1
  for (int kc = 0; kc < 8; ++kc) {
    f16x8 af[4], bv[4];
#pragma unroll
    for (int mi = 0; mi < 4; ++mi)
      af[mi] = *reinterpret_cast<const f16x8*>(aP + mi * 512);
#pragma unroll
    for (int nj = 0; nj < 4; ++nj)
      bv[nj] = *reinterpret_cast<const f16x8*>(bP + nj * 512);
    aP += 2048; bP += 2048;
#pragma unroll
    for (int mi = 0; mi < 4; ++mi)
#pragma unroll
      for (int nj = 0; nj < 4; ++nj)
        acc[mi][nj] = __builtin_amdgcn_mfma_f32_16x16x32_f16(af[mi], bv[nj],
                                                             acc[mi][nj], 0, 0, 0);
  }

  // epilogue: d = fmaf(-2^-11, acc, zn+en), top-2 within this 128-e tile
  float znr[4][4];
#pragma unroll
  for (int mi = 0; mi < 4; ++mi)
#pragma unroll
    for (int rg = 0; rg < 4; ++rg)
      znr[mi][rg] = znorm[n0 + wr * 64 + mi * 16 + g * 4 + rg];

  float bestd[4][4], b2d[4][4]; int besti[4][4];
#pragma unroll
  for (int mi = 0; mi < 4; ++mi)
#pragma unroll
    for (int rg = 0; rg < 4; ++rg) { bestd[mi][rg] = 3.4e38f; b2d[mi][rg] = 3.4e38f; besti[mi][rg] = 0; }

#pragma unroll
  for (int nj = 0; nj < 4; ++nj) {
    int e = e0 + wc * 64 + nj * 16 + l15;
    float en = enorm[e];
#pragma unroll
    for (int mi = 0; mi < 4; ++mi)
#pragma unroll
      for (int rg = 0; rg < 4; ++rg) {
        float d = fmaf(NEG2_SCALE, acc[mi][nj][rg], __fadd_rn(znr[mi][rg], en));
        if (d < bestd[mi][rg]) {
          b2d[mi][rg] = bestd[mi][rg]; bestd[mi][rg] = d; besti[mi][rg] = e;
        } else if (d < b2d[mi][rg]) {
          b2d[mi][rg] = d;
        }
      }
  }

#pragma unroll
  for (int mi = 0; mi < 4; ++mi)
#pragma unroll
    for (int rg = 0; rg < 4; ++rg) {
      float bd = bestd[mi][rg]; int bi = besti[mi][rg]; float b2 = b2d[mi][rg];
#pragma unroll
      for (int m = 1; m < 16; m <<= 1) {
        float od = __shfl_xor(bd, m, 64);
        int   oi = __shfl_xor(bi, m, 64);
        float o2 = __shfl_xor(b2, m, 64);
        float hi = fmaxf(bd, od);
        b2 = fminf(fminf(b2, o2), hi);
        if (od < bd || (od == bd && oi < bi)) { bd = od; bi = oi; }
      }
      if (l15 == 0) {
        int lr = wr * 64 + mi * 16 + g * 4 + rg;
        redd[lr * 2 + wc] = bd; redi[lr * 2 + wc] = bi; red2[lr * 2 + wc] = b2;
      }
    }
  __syncthreads();

  if (tid < 128) {
    float d0 = redd[tid * 2], d1 = redd[tid * 2 + 1];
    int   i0 = redi[tid * 2], i1 = redi[tid * 2 + 1];
    float s0 = red2[tid * 2], s1 = red2[tid * 2 + 1];
    float bd; int bi;
    if (d1 < d0 || (d1 == d0 && i1 < i0)) { bd = d1; bi = i1; } else { bd = d0; bi = i0; }
    float b2 = fminf(fminf(s0, s1), fmaxf(d0, d1));
    size_t o = (size_t)(n0 + tid) * 8 + nb;
    pbd[o] = bd; pbi[o] = bi; pb2[o] = b2;
  }
}

// ---------------------------------------------------------------------------
// merge 8 per-block top-2 candidates per row; exact first-index tie-break
__global__ __launch_bounds__(256) void merge_kernel(
    const float* __restrict__ pbd, const int* __restrict__ pbi,
    const float* __restrict__ pb2,
    int* __restrict__ idx_out, float* __restrict__ loss_part,
    int* __restrict__ flag_cnt, int* __restrict__ flag_list) {
  int n = blockIdx.x * 256 + threadIdx.x;
  float bd = 3.4e38f; int bi = 0x7FFFFFFF; int bnb = -1;
#pragma unroll
  for (int nb = 0; nb < 8; ++nb) {
    float d = pbd[(size_t)n * 8 + nb];
    int   i = pbi[(size_t)n * 8 + nb];
    if (d < bd || (d == bd && i < bi)) { bd = d; bi = i; bnb = nb; }
  }
  float b2 = 3.4e38f;
#pragma unroll
  for (int nb = 0; nb < 8; ++nb) {
    float v = (nb == bnb) ? pb2[(size_t)n * 8 + nb] : pbd[(size_t)n * 8 + nb];
    b2 = fminf(b2, v);
  }
  idx_out[n] = bi;
  loss_part[n] = bd;
  if (b2 - bd < THETA) {
    int p = atomicAdd(flag_cnt, 1);
    flag_list[p] = n;
  }
}

// ---------------------------------------------------------------------------
// coalesced exact-fp32 repair: 4 flagged rows per block share one embT
// stream; per-row fmaf chain identical to the r1-certified arithmetic.
__global__ __launch_bounds__(256) void repair_kernel(
    const float* __restrict__ z, const float* __restrict__ embT,
    const float* __restrict__ znorm, const float* __restrict__ enorm,
    const int* __restrict__ flag_cnt, const int* __restrict__ flag_list,
    int* __restrict__ idx_out) {
  __shared__ float zrow[4][256];
  __shared__ float rd[256];
  __shared__ int   ri[256];
  const int t = threadIdx.x;
  const int cnt = flag_cnt[0] < NROWS ? flag_cnt[0] : NROWS;
  const int nquad = (cnt + 3) >> 2;
  const float4* embT4 = reinterpret_cast<const float4*>(embT);
  for (int j = blockIdx.x; j < nquad; j += gridDim.x) {
    int nr[4];
    __syncthreads();
#pragma unroll
    for (int r = 0; r < 4; ++r) {
      int jr = j * 4 + r;
      nr[r] = flag_list[jr < cnt ? jr : cnt - 1];
      zrow[r][t] = z[(size_t)(nr[r] >> 10) * ZB_STRIDE + (size_t)t * 1024 + (nr[r] & 1023)];
    }
    __syncthreads();
    float4 dot[4] = {{0.f,0.f,0.f,0.f},{0.f,0.f,0.f,0.f},{0.f,0.f,0.f,0.f},{0.f,0.f,0.f,0.f}};
    for (int k = 0; k < 256; ++k) {
      float4 v = embT4[k * 256 + t];
#pragma unroll
      for (int r = 0; r < 4; ++r) {
        float s = zrow[r][k];
        dot[r].x = fmaf(s, v.x, dot[r].x);
        dot[r].y = fmaf(s, v.y, dot[r].y);
        dot[r].z = fmaf(s, v.z, dot[r].z);
        dot[r].w = fmaf(s, v.w, dot[r].w);
      }
    }
#pragma unroll 1
    for (int r = 0; r < 4; ++r) {
      const float zn = znorm[nr[r]];
      float bd = 3.4e38f; int bi = 0;
      const float dv[4] = {dot[r].x, dot[r].y, dot[r].z, dot[r].w};
#pragma unroll
      for (int q = 0; q < 4; ++q) {
        int e = t * 4 + q;
        float d = __fsub_rn(__fadd_rn(zn, enorm[e]), __fmul_rn(2.0f, dv[q]));
        if (d < bd) { bd = d; bi = e; }
      }
      rd[t] = bd; ri[t] = bi;
      __syncthreads();
      for (int s2 = 128; s2 > 0; s2 >>= 1) {
        if (t < s2) {
          float od = rd[t + s2]; int oi = ri[t + s2];
          if (od < rd[t] || (od == rd[t] && oi < ri[t])) { rd[t] = od; ri[t] = oi; }
        }
        __syncthreads();
      }
      if (t == 0) idx_out[nr[r]] = ri[0];
      __syncthreads();
    }
  }
}

// ---------------------------------------------------------------------------
// Fused outputs (role-split): all 2048 blocks: one-hot streaming write;
// blocks [0,1024): z_q gather; blocks [1024,1152): idx-as-float + histogram.
__global__ __launch_bounds__(256) void outputs_kernel(const int* __restrict__ idx,
                                                      const float* __restrict__ emb,
                                                      float* __restrict__ out_enc,
                                                      float* __restrict__ out_idxf,
                                                      int* __restrict__ hist,
                                                      float* __restrict__ zq_out) {
  const int t = threadIdx.x;
  for (int i = blockIdx.x * 256 + t; i < NROWS * 256; i += 2048 * 256) {
    int n = i >> 8, j4 = i & 255;
    int e = idx[n];
    float4 v = {0.f, 0.f, 0.f, 0.f};
    if ((e >> 2) == j4) ((float*)&v)[e & 3] = 1.0f;
    reinterpret_cast<float4*>(out_enc)[i] = v;
  }
  if (blockIdx.x < 1024) {
    int bh = blockIdx.x;
    int b = bh >> 5, h = bh & 31;
    int ww = t & 31;
    int gg = t >> 5;
    int n = b * 1024 + h * 32 + ww;
    int e = idx[n];
    const float* eb = emb + (size_t)e * CDIM;
    float* ob = zq_out + (size_t)b * ZB_STRIDE + h * 32 + ww;
#pragma unroll
    for (int u = 0; u < 32; ++u) {
      int c = gg * 32 + u;
      ob[(size_t)c * 1024] = eb[c];
    }
  } else if (blockIdx.x < 1152) {
    int n = (blockIdx.x - 1024) * 256 + t;
    int e = idx[n];
    out_idxf[n] = (float)e;
    atomicAdd(&hist[e], 1);
  }
}

__global__ __launch_bounds__(256) void finalize_kernel(const float* __restrict__ loss_part,
                                                       const int* __restrict__ hist,
                                                       float* __restrict__ out_loss,
                                                       float* __restrict__ out_perp) {
  __shared__ float red[256];
  int t = threadIdx.x;
  float sum = 0.f;
  for (int i = t; i < NROWS; i += 256) sum += loss_part[i];
  red[t] = sum;
  __syncthreads();
  for (int s2 = 128; s2 > 0; s2 >>= 1) {
    if (t < s2) red[t] += red[t + s2];
    __syncthreads();
  }
  if (t == 0) out_loss[0] = 1.25f * (red[0] / 8388608.0f);
  __syncthreads();
  float hs = 0.f;
  for (int i = t; i < 1024; i += 256) {
    float em = (float)hist[i] / 32768.0f;
    hs += em * logf(em + 1e-10f);
  }
  red[t] = hs;
  __syncthreads();
  for (int s2 = 128; s2 > 0; s2 >>= 1) {
    if (t < s2) red[t] += red[t + s2];
    __syncthreads();
  }
  if (t == 0) out_perp[0] = expf(-red[0]);
}

// ---------------------------------------------------------------------------
extern "C" void kernel_launch(void* const* d_in, const int* in_sizes, int n_in,
                              void* d_out, int out_size, void* d_ws, size_t ws_size,
                              hipStream_t stream) {
  const float* z   = (const float*)d_in[0];
  const float* emb = (const float*)d_in[1];
  float* out = (float*)d_out;

  float* out_zq   = out + ZQ_OFF;
  float* out_loss = out + LOSS_OFF;
  float* out_perp = out + PERP_OFF;
  float* out_enc  = out + ENC_OFF;
  float* out_idxf = out + IDX_OFF;

  // workspace (small)
  int*   idx       = (int*)d_ws;                   // 32768
  int*   hist      = idx + NROWS;                  // 1024
  int*   flag_cnt  = hist + NE;                    // 4 (1 used)
  int*   flag_list = flag_cnt + 4;                 // 32768
  float* loss_part = (float*)(flag_list + NROWS);  // 32768
  float* znorm     = loss_part + NROWS;            // 32768
  float* enorm     = znorm + NROWS;                // 1024

  // staging buffers carved from the one-hot output region (overwritten later)
  unsigned short* zf16r = (unsigned short*)(out_enc + 2);    // 8388608 u16 (16B-aligned)
  unsigned short* ef16r = zf16r + (size_t)NROWS * CDIM;      // 262144 u16
  float*          embT  = (float*)(ef16r + (size_t)NE * CDIM);// 262144 f32
  float*          pbd   = embT + 262144;                     // 262144 f32
  int*            pbi   = (int*)(pbd + 262144);              // 262144 i32
  float*          pb2   = (float*)(pbi + 262144);            // 262144 f32

  // hist (NE ints) and flag_cnt (adjacent) in one memset
  hipMemsetAsync(hist, 0, (NE + 1) * sizeof(int), stream);

  convert_z_kernel<<<512, 256, 0, stream>>>(z, zf16r, znorm);
  prep_e<<<388, 256, 0, stream>>>(emb, ef16r, embT, enorm);
  argmin_tile<<<2048, 256, 0, stream>>>(zf16r, ef16r, znorm, enorm, pbd, pbi, pb2);
  merge_kernel<<<NROWS / 256, 256, 0, stream>>>(pbd, pbi, pb2, idx, loss_part, flag_cnt, flag_list);
  repair_kernel<<<256, 256, 0, stream>>>(z, embT, znorm, enorm, flag_cnt, flag_list, idx);
  outputs_kernel<<<2048, 256, 0, stream>>>(idx, emb, out_enc, out_idxf, hist, out_zq);
  finalize_kernel<<<1, 256, 0, stream>>>(loss_part, hist, out_loss, out_perp);
}